// Round 2
// baseline (305.478 us; speedup 1.0000x reference)
//
#include <hip/hip_runtime.h>
#include <math.h>

#define D     2048
#define NR    32
#define ROWS  8
#define CU    34            // uints per 64-j chunk: 32 payload + 2 pad (even -> aligned uint2)
#define XRU   (32 * CU)     // 1088 uints per row

__device__ __forceinline__ unsigned int f2bf(float f) {
    unsigned int u = __float_as_uint(f);
    return (u + 0x7FFFu + ((u >> 16) & 1u)) >> 16;   // RNE bf16, low 16 bits
}
__device__ __forceinline__ float bflo(unsigned int p) { return __uint_as_float(p << 16); }
__device__ __forceinline__ float bfhi(unsigned int p) { return __uint_as_float(p & 0xFFFF0000u); }

__device__ __forceinline__ void fma4(float a, const float4& w, float4& o) {
    o.x = fmaf(a, w.x, o.x);
    o.y = fmaf(a, w.y, o.y);
    o.z = fmaf(a, w.z, o.z);
    o.w = fmaf(a, w.w, o.w);
}

__device__ __forceinline__ float wred(float v) {
    #pragma unroll
    for (int off = 32; off >= 1; off >>= 1) v += __shfl_xor(v, off);
    return v;
}

// ---------------- prep: wdp = gamma (.) wd ; c1 = colsum(wdp) ; c2 = colsum(beta (.) wd) ----
__global__ __launch_bounds__(256)
void k_prep(const float* __restrict__ wd, const float* __restrict__ gamma,
            const float* __restrict__ beta, float* __restrict__ wdp,
            float* __restrict__ c12p)
{
    __shared__ float red[4][64];
    const int tid = threadIdx.x;
    const int l = tid & 63, w = tid >> 6;
    const int j = blockIdx.x * 256 + tid;

    const float gv = gamma[j], bv = beta[j];
    float4 c1a[8], c2a[8];
    #pragma unroll
    for (int q = 0; q < 8; ++q) {
        float4 wv = *(const float4*)(wd + j * NR + q * 4);
        float4 wp = make_float4(gv * wv.x, gv * wv.y, gv * wv.z, gv * wv.w);
        *(float4*)(wdp + j * NR + q * 4) = wp;
        c1a[q] = wp;
        c2a[q] = make_float4(bv * wv.x, bv * wv.y, bv * wv.z, bv * wv.w);
    }
    #pragma unroll
    for (int q = 0; q < 8; ++q) {
        c1a[q].x = wred(c1a[q].x); c1a[q].y = wred(c1a[q].y);
        c1a[q].z = wred(c1a[q].z); c1a[q].w = wred(c1a[q].w);
        c2a[q].x = wred(c2a[q].x); c2a[q].y = wred(c2a[q].y);
        c2a[q].z = wred(c2a[q].z); c2a[q].w = wred(c2a[q].w);
    }
    if (l == 0) {
        #pragma unroll
        for (int q = 0; q < 8; ++q) {
            red[w][q * 4 + 0] = c1a[q].x; red[w][q * 4 + 1] = c1a[q].y;
            red[w][q * 4 + 2] = c1a[q].z; red[w][q * 4 + 3] = c1a[q].w;
            red[w][32 + q * 4 + 0] = c2a[q].x; red[w][32 + q * 4 + 1] = c2a[q].y;
            red[w][32 + q * 4 + 2] = c2a[q].z; red[w][32 + q * 4 + 3] = c2a[q].w;
        }
    }
    __syncthreads();
    if (tid < 64)
        c12p[blockIdx.x * 64 + tid] = red[0][tid] + red[1][tid] + red[2][tid] + red[3][tid];
}

// ---------------- fused: LN-folded down-proj + GELU + up-proj + residual, 8 rows/block ----
// LDS ~40 KB -> 4 blocks/CU (16 waves/CU). x staged bf16 for the GEMM; residual re-reads
// fp32 x from global (L2/L3-hot).
__global__ __launch_bounds__(256, 4)
void k_fused(const float* __restrict__ x, const float* __restrict__ bd,
             const float* __restrict__ wu, const float* __restrict__ bu,
             const float* __restrict__ wdp, const float* __restrict__ c12p,
             float* __restrict__ out)
{
    __shared__ unsigned int xs[ROWS * XRU];   // 34816 B, bf16-packed x
    __shared__ float S4[4][ROWS][NR];         // per-wave down-proj partials (4 KB)
    __shared__ float a_s[ROWS][NR];           // gelu activations (1 KB)
    __shared__ float mu_s[ROWS], rs_s[ROWS];
    __shared__ float c1s[NR], c2s[NR], bds[NR];

    const int tid = threadIdx.x;
    const int w = tid >> 6, l = tid & 63;
    const long row0 = (long)blockIdx.x * ROWS;

    if (tid < NR) {
        float a1 = 0.f, a2 = 0.f;
        #pragma unroll
        for (int p = 0; p < 8; ++p) {
            a1 += c12p[p * 64 + tid];
            a2 += c12p[p * 64 + 32 + tid];
        }
        c1s[tid] = a1; c2s[tid] = a2; bds[tid] = bd[tid];
    }

    // ---- Phase A: stream x once, stats in fp32, store bf16-packed to LDS ----
    #pragma unroll
    for (int rp = 0; rp < 2; ++rp) {
        const int row = w * 2 + rp;
        const float* xr = x + (row0 + row) * D;
        float s = 0.f, s2 = 0.f;
        #pragma unroll
        for (int it = 0; it < 8; ++it) {
            const int j = it * 256 + l * 4;
            float4 v = *(const float4*)(xr + j);
            uint2 p;
            p.x = f2bf(v.x) | (f2bf(v.y) << 16);
            p.y = f2bf(v.z) | (f2bf(v.w) << 16);
            *(uint2*)&xs[row * XRU + (j >> 6) * CU + ((j & 63) >> 1)] = p;
            s  += v.x + v.y + v.z + v.w;
            s2 += v.x * v.x + v.y * v.y + v.z * v.z + v.w * v.w;
        }
        #pragma unroll
        for (int off = 32; off >= 1; off >>= 1) {
            s  += __shfl_xor(s, off);
            s2 += __shfl_xor(s2, off);
        }
        if (l == 0) {
            const float mu  = s * (1.0f / D);
            const float var = s2 * (1.0f / D) - mu * mu;
            mu_s[row] = mu;
            rs_s[row] = rsqrtf(var + 1e-5f);
        }
    }
    __syncthreads();

    // ---- Phase B: S[row][r] = sum_j x[row][j] * wdp[j][r]  (raw x; LN folded out) ----
    {
        const int rg = tid & 7, r0 = rg * 4, jo = tid >> 3;   // jo in 0..31, 64 j's each
        float4 acc[ROWS];
        #pragma unroll
        for (int m = 0; m < ROWS; ++m) acc[m] = make_float4(0.f, 0.f, 0.f, 0.f);

        const float* wp_base = wdp + (jo * 64) * NR + r0;
        const unsigned int* xb = xs + jo * CU;
        #pragma unroll 4
        for (int tq = 0; tq < 16; ++tq) {
            const float4 w0 = *(const float4*)(wp_base + (tq * 4 + 0) * NR);
            const float4 w1 = *(const float4*)(wp_base + (tq * 4 + 1) * NR);
            const float4 w2 = *(const float4*)(wp_base + (tq * 4 + 2) * NR);
            const float4 w3 = *(const float4*)(wp_base + (tq * 4 + 3) * NR);
            #pragma unroll
            for (int m = 0; m < ROWS; ++m) {
                const uint2 hp = *(const uint2*)&xb[m * XRU + tq * 2];
                fma4(bflo(hp.x), w0, acc[m]);
                fma4(bfhi(hp.x), w1, acc[m]);
                fma4(bflo(hp.y), w2, acc[m]);
                fma4(bfhi(hp.y), w3, acc[m]);
            }
        }
        // reduce over the 8 jo-shards inside this wave (lane bits 3..5)
        #pragma unroll
        for (int m = 0; m < ROWS; ++m) {
            #pragma unroll
            for (int off = 8; off <= 32; off <<= 1) {
                acc[m].x += __shfl_xor(acc[m].x, off);
                acc[m].y += __shfl_xor(acc[m].y, off);
                acc[m].z += __shfl_xor(acc[m].z, off);
                acc[m].w += __shfl_xor(acc[m].w, off);
            }
        }
        if (l < 8) {
            #pragma unroll
            for (int m = 0; m < ROWS; ++m)
                *(float4*)&S4[w][m][l * 4] = acc[m];
        }
    }
    __syncthreads();

    // ---- GELU: y = rstd*(S - mu*c1) + c2 + bd ; a = gelu(y) ----
    {
        const int m = tid >> 5, r = tid & 31;   // 256 threads == 8 rows x 32 r
        const float S = S4[0][m][r] + S4[1][m][r] + S4[2][m][r] + S4[3][m][r];
        const float y = rs_s[m] * (S - mu_s[m] * c1s[r]) + c2s[r] + bds[r];
        a_s[m][r] = 0.5f * y * (1.0f + erff(y * 0.70710678118654752f));
    }
    __syncthreads();

    // ---- Phase C: out[row][j] = x[row][j] + bu[j] + sum_r a[row][r] * wu[r][j] ----
    #pragma unroll 1
    for (int c = 0; c < 2; ++c) {
        const int j = c * 1024 + tid * 4;
        const float4 bv = *(const float4*)(bu + j);
        float4 o[ROWS];
        #pragma unroll
        for (int m = 0; m < ROWS; ++m) {
            const float4 xv = *(const float4*)(x + (row0 + m) * D + j);   // L2/L3-hot re-read
            o[m] = make_float4(xv.x + bv.x, xv.y + bv.y, xv.z + bv.z, xv.w + bv.w);
        }
        #pragma unroll 4
        for (int rq = 0; rq < 8; ++rq) {
            float4 ar[ROWS];
            #pragma unroll
            for (int m = 0; m < ROWS; ++m)
                ar[m] = *(const float4*)&a_s[m][rq * 4];   // block-uniform broadcast
            #pragma unroll
            for (int rr = 0; rr < 4; ++rr) {
                const float4 wv = *(const float4*)(wu + (rq * 4 + rr) * D + j);
                #pragma unroll
                for (int m = 0; m < ROWS; ++m) {
                    const float av = (rr == 0) ? ar[m].x : (rr == 1) ? ar[m].y
                                   : (rr == 2) ? ar[m].z : ar[m].w;
                    fma4(av, wv, o[m]);
                }
            }
        }
        #pragma unroll
        for (int m = 0; m < ROWS; ++m) {
            float* op = out + (row0 + m) * D + j;
            __builtin_nontemporal_store(o[m].x, op + 0);
            __builtin_nontemporal_store(o[m].y, op + 1);
            __builtin_nontemporal_store(o[m].z, op + 2);
            __builtin_nontemporal_store(o[m].w, op + 3);
        }
    }
}

extern "C" void kernel_launch(void* const* d_in, const int* in_sizes, int n_in,
                              void* d_out, int out_size, void* d_ws, size_t ws_size,
                              hipStream_t stream) {
    (void)n_in; (void)ws_size; (void)out_size;
    const float* x     = (const float*)d_in[0];
    const float* gamma = (const float*)d_in[1];
    const float* beta  = (const float*)d_in[2];
    const float* wd    = (const float*)d_in[3];
    const float* bd    = (const float*)d_in[4];
    const float* wu    = (const float*)d_in[5];
    const float* bu    = (const float*)d_in[6];
    float* out  = (float*)d_out;
    float* wdp  = (float*)d_ws;          // 2048*32 fp32 = 256 KB
    float* c12p = wdp + D * NR;          // 8 blocks * 64 partials

    const int nrows  = in_sizes[0] / D;  // 16384
    const int blocks = nrows / ROWS;     // 2048

    hipLaunchKernelGGL(k_prep,  dim3(8),      dim3(256), 0, stream, wd, gamma, beta, wdp, c12p);
    hipLaunchKernelGGL(k_fused, dim3(blocks), dim3(256), 0, stream, x, bd, wu, bu, wdp, c12p, out);
}

// Round 3
// 287.511 us; speedup vs baseline: 1.0625x; 1.0625x over previous
//
#include <hip/hip_runtime.h>
#include <math.h>

#define D     2048
#define NR    32
#define ROWS  8

typedef short bf16x8 __attribute__((ext_vector_type(8)));
typedef float f32x4  __attribute__((ext_vector_type(4)));

__device__ __forceinline__ unsigned int f2bf(float f) {
    unsigned int u = __float_as_uint(f);
    return (u + 0x7FFFu + ((u >> 16) & 1u)) >> 16;   // RNE bf16, low 16
}
__device__ __forceinline__ unsigned int pk2(float a, float b) {
    return f2bf(a) | (f2bf(b) << 16);
}

// ---------------- prep: build fragment-layout bf16 weights + LN-fold vectors ----------------
// blocks 0..127: wuf[tile t][lane l][e] = bf16(wu[(l>>4)*8+e][t*16 + (l&15)])
// blocks 128..255: wdpf[(kk,n)][lane l][e] = bf16(gamma[k]*wd[k][n*16+(l&15)]), k=kk*32+(l>>4)*8+e
//                  + partial c1 (colsum gamma.wd) / c2 (colsum beta.wd) per (kk,n)
__global__ __launch_bounds__(64)
void k_prep(const float* __restrict__ wd, const float* __restrict__ gamma,
            const float* __restrict__ beta, const float* __restrict__ wu,
            unsigned int* __restrict__ wuf, unsigned int* __restrict__ wdpf,
            float* __restrict__ c12p)
{
    const int l = threadIdx.x;
    const int q = l >> 4, p = l & 15;
    const int b = blockIdx.x;
    if (b < 128) {
        const int t = b;
        float v[8];
        #pragma unroll
        for (int e = 0; e < 8; ++e)
            v[e] = wu[(q * 8 + e) * D + t * 16 + p];
        uint4 pk;
        pk.x = pk2(v[0], v[1]); pk.y = pk2(v[2], v[3]);
        pk.z = pk2(v[4], v[5]); pk.w = pk2(v[6], v[7]);
        *(uint4*)&wuf[(t * 64 + l) * 4] = pk;
    } else {
        const int idx = b - 128;           // 0..127 -> (kk, n)
        const int kk = idx >> 1, n = idx & 1;
        const int r = n * 16 + p;
        float wv[8];
        float c1 = 0.f, c2 = 0.f;
        #pragma unroll
        for (int e = 0; e < 8; ++e) {
            const int k = kk * 32 + q * 8 + e;
            const float wdv = wd[k * NR + r];
            wv[e] = gamma[k] * wdv;
            c1 += wv[e];
            c2 += beta[k] * wdv;
        }
        uint4 pk;
        pk.x = pk2(wv[0], wv[1]); pk.y = pk2(wv[2], wv[3]);
        pk.z = pk2(wv[4], wv[5]); pk.w = pk2(wv[6], wv[7]);
        *(uint4*)&wdpf[(idx * 64 + l) * 4] = pk;
        c1 += __shfl_xor(c1, 16); c1 += __shfl_xor(c1, 32);
        c2 += __shfl_xor(c2, 16); c2 += __shfl_xor(c2, 32);
        if (q == 0) {
            c12p[idx * 32 + p]      = c1;
            c12p[idx * 32 + 16 + p] = c2;
        }
    }
}

// ---------------- reduce c12 partials: c12[0..31]=c1, c12[32..63]=c2 ----------------
__global__ __launch_bounds__(64)
void k_c12(const float* __restrict__ c12p, float* __restrict__ c12)
{
    const int i = threadIdx.x;
    const int half = i >> 5, r = i & 31;
    const int n = r >> 4, rr = r & 15;
    float s = 0.f;
    for (int kk = 0; kk < 64; ++kk)
        s += c12p[(kk * 2 + n) * 32 + half * 16 + rr];
    c12[i] = s;
}

// ---------------- fused: LN-folded down-proj + GELU + up-proj + residual (MFMA) ----------------
__global__ __launch_bounds__(256, 4)
void k_fused(const float* __restrict__ x, const float* __restrict__ bd,
             const float* __restrict__ bu, const unsigned int* __restrict__ wuf,
             const unsigned int* __restrict__ wdpf, const float* __restrict__ c12,
             float* __restrict__ out)
{
    __shared__ unsigned int xs[ROWS * 1024];      // 32 KB bf16 x, XOR-swizzled rows
    __shared__ float Sp[4][2][16][8];             // 4 KB down-proj partials [w][n][col][m]
    __shared__ unsigned short a_sh[ROWS][NR];     // 512 B activations bf16
    __shared__ float mu_s[ROWS], rs_s[ROWS];

    const int tid = threadIdx.x;
    const int w = tid >> 6, l = tid & 63;
    const int p = l & 15, q = l >> 4;
    const long row0 = (long)blockIdx.x * ROWS;

    // ---- Phase A: stream x once, fp32 stats, bf16 pack -> LDS (swizzled) ----
    #pragma unroll
    for (int rp = 0; rp < 2; ++rp) {
        const int row = w * 2 + rp;
        const float* xr = x + (row0 + row) * D;
        float s = 0.f, s2 = 0.f;
        #pragma unroll
        for (int it = 0; it < 8; ++it) {
            const int j = it * 256 + l * 4;
            float4 v = *(const float4*)(xr + j);
            uint2 pkk;
            pkk.x = pk2(v.x, v.y);
            pkk.y = pk2(v.z, v.w);
            const int byte = (row * 4096 + j * 2) ^ (row << 4);
            *(uint2*)((char*)xs + byte) = pkk;
            s  += v.x + v.y + v.z + v.w;
            s2 += v.x * v.x + v.y * v.y + v.z * v.z + v.w * v.w;
        }
        #pragma unroll
        for (int off = 32; off >= 1; off >>= 1) {
            s  += __shfl_xor(s, off);
            s2 += __shfl_xor(s2, off);
        }
        if (l == 0) {
            const float mu  = s * (1.0f / D);
            const float var = s2 * (1.0f / D) - mu * mu;
            mu_s[row] = mu;
            rs_s[row] = rsqrtf(var + 1e-5f);
        }
    }
    __syncthreads();

    // ---- Phase B: S = x @ wdp via MFMA, K split over 4 waves ----
    {
        f32x4 acc0 = {0.f, 0.f, 0.f, 0.f}, acc1 = {0.f, 0.f, 0.f, 0.f};
        const bool arow = p < ROWS;
        #pragma unroll 4
        for (int t = 0; t < 16; ++t) {
            bf16x8 af = {0, 0, 0, 0, 0, 0, 0, 0};
            if (arow) {
                const int byte = (p * 4096 + (w * 512 + t * 32) * 2 + q * 16) ^ (p << 4);
                af = *(const bf16x8*)((const char*)xs + byte);
            }
            const int base = (w * 16 + t) * 512 + l * 4;
            const bf16x8 b0 = *(const bf16x8*)&wdpf[base];
            const bf16x8 b1 = *(const bf16x8*)&wdpf[base + 256];
            acc0 = __builtin_amdgcn_mfma_f32_16x16x32_bf16(af, b0, acc0, 0, 0, 0);
            acc1 = __builtin_amdgcn_mfma_f32_16x16x32_bf16(af, b1, acc1, 0, 0, 0);
        }
        if (l < 32) {   // D rows m=(l>>4)*4+reg < 8 live in lanes 0..31
            *(f32x4*)&Sp[w][0][p][(q & 1) * 4] = acc0;
            *(f32x4*)&Sp[w][1][p][(q & 1) * 4] = acc1;
        }
    }
    __syncthreads();

    // ---- GELU: y = rstd*(S - mu*c1) + c2 + bd ; a = gelu(y) -> bf16 ----
    {
        const int m = tid >> 5, r = tid & 31;
        const int n = r >> 4, rr = r & 15;
        const float S = Sp[0][n][rr][m] + Sp[1][n][rr][m]
                      + Sp[2][n][rr][m] + Sp[3][n][rr][m];
        const float y = rs_s[m] * (S - mu_s[m] * c12[r]) + c12[32 + r] + bd[r];
        const float a = 0.5f * y * (1.0f + erff(y * 0.70710678118654752f));
        a_sh[m][r] = (unsigned short)f2bf(a);
    }
    __syncthreads();

    // ---- Phase C: out = x + bu + (a @ wu), computed transposed so each lane owns 4
    // consecutive j of one out row (float4 residual read + store) ----
    {
        bf16x8 afc = {0, 0, 0, 0, 0, 0, 0, 0};
        if (p < ROWS) afc = *(const bf16x8*)((const char*)a_sh + p * 64 + q * 16);
        const bool act = p < ROWS;
        const long xbase = (row0 + p) * D;
        const f32x4 z = {0.f, 0.f, 0.f, 0.f};
        #pragma unroll 4
        for (int t = 0; t < 32; ++t) {
            const int j0 = w * 512 + t * 16;
            const bf16x8 bw = *(const bf16x8*)&wuf[(j0 >> 4) * 256 + l * 4];
            f32x4 dd = __builtin_amdgcn_mfma_f32_16x16x32_bf16(bw, afc, z, 0, 0, 0);
            if (act) {
                const int jj = j0 + q * 4;
                const float4 xv = *(const float4*)(x + xbase + jj);   // L2-hot re-read
                const float4 bv = *(const float4*)(bu + jj);
                float* op = out + xbase + jj;
                __builtin_nontemporal_store(xv.x + bv.x + dd[0], op + 0);
                __builtin_nontemporal_store(xv.y + bv.y + dd[1], op + 1);
                __builtin_nontemporal_store(xv.z + bv.z + dd[2], op + 2);
                __builtin_nontemporal_store(xv.w + bv.w + dd[3], op + 3);
            }
        }
    }
}

extern "C" void kernel_launch(void* const* d_in, const int* in_sizes, int n_in,
                              void* d_out, int out_size, void* d_ws, size_t ws_size,
                              hipStream_t stream) {
    (void)n_in; (void)ws_size; (void)out_size;
    const float* x     = (const float*)d_in[0];
    const float* gamma = (const float*)d_in[1];
    const float* beta  = (const float*)d_in[2];
    const float* wd    = (const float*)d_in[3];
    const float* bd    = (const float*)d_in[4];
    const float* wu    = (const float*)d_in[5];
    const float* bu    = (const float*)d_in[6];
    float* out = (float*)d_out;

    unsigned int* wuf  = (unsigned int*)d_ws;      // 128 KB
    unsigned int* wdpf = wuf + 32768;              // 128 KB
    float* c12p = (float*)(wdpf + 32768);          // 16 KB
    float* c12  = c12p + 4096;                     // 256 B

    const int nrows  = in_sizes[0] / D;            // 16384
    const int blocks = nrows / ROWS;               // 2048

    hipLaunchKernelGGL(k_prep,  dim3(256),    dim3(64),  0, stream,
                       wd, gamma, beta, wu, wuf, wdpf, c12p);
    hipLaunchKernelGGL(k_c12,   dim3(1),      dim3(64),  0, stream, c12p, c12);
    hipLaunchKernelGGL(k_fused, dim3(blocks), dim3(256), 0, stream,
                       x, bd, bu, wuf, wdpf, c12, out);
}

// Round 5
// 274.323 us; speedup vs baseline: 1.1136x; 1.0481x over previous
//
#include <hip/hip_runtime.h>
#include <math.h>

#define D     2048
#define NR    32
#define ROWS  16

typedef short bf16x8 __attribute__((ext_vector_type(8)));
typedef float f32x4  __attribute__((ext_vector_type(4)));

__device__ __forceinline__ unsigned int f2bf(float f) {
    unsigned int u = __float_as_uint(f);
    return (u + 0x7FFFu + ((u >> 16) & 1u)) >> 16;   // RNE bf16, low 16
}
__device__ __forceinline__ unsigned int pk2(float a, float b) {
    return f2bf(a) | (f2bf(b) << 16);
}

// ---------------- prep: build fragment-layout bf16 weights + LN-fold vectors ----------------
// blocks 0..127: wuf[tile t][lane l][e] = bf16(wu[(l>>4)*8+e][t*16 + (l&15)])
// blocks 128..255: wdpf[(kk,n)][lane l][e] = bf16(gamma[k]*wd[k][n*16+(l&15)]), k=kk*32+(l>>4)*8+e
//                  + partial c1 (colsum gamma.wd) / c2 (colsum beta.wd) per (kk,n)
__global__ __launch_bounds__(64)
void k_prep(const float* __restrict__ wd, const float* __restrict__ gamma,
            const float* __restrict__ beta, const float* __restrict__ wu,
            unsigned int* __restrict__ wuf, unsigned int* __restrict__ wdpf,
            float* __restrict__ c12p)
{
    const int l = threadIdx.x;
    const int q = l >> 4, p = l & 15;
    const int b = blockIdx.x;
    if (b < 128) {
        const int t = b;
        float v[8];
        #pragma unroll
        for (int e = 0; e < 8; ++e)
            v[e] = wu[(q * 8 + e) * D + t * 16 + p];
        uint4 pk;
        pk.x = pk2(v[0], v[1]); pk.y = pk2(v[2], v[3]);
        pk.z = pk2(v[4], v[5]); pk.w = pk2(v[6], v[7]);
        *(uint4*)&wuf[(t * 64 + l) * 4] = pk;
    } else {
        const int idx = b - 128;           // 0..127 -> (kk, n)
        const int kk = idx >> 1, n = idx & 1;
        const int r = n * 16 + p;
        float wv[8];
        float c1 = 0.f, c2 = 0.f;
        #pragma unroll
        for (int e = 0; e < 8; ++e) {
            const int k = kk * 32 + q * 8 + e;
            const float wdv = wd[k * NR + r];
            wv[e] = gamma[k] * wdv;
            c1 += wv[e];
            c2 += beta[k] * wdv;
        }
        uint4 pk;
        pk.x = pk2(wv[0], wv[1]); pk.y = pk2(wv[2], wv[3]);
        pk.z = pk2(wv[4], wv[5]); pk.w = pk2(wv[6], wv[7]);
        *(uint4*)&wdpf[(idx * 64 + l) * 4] = pk;
        c1 += __shfl_xor(c1, 16); c1 += __shfl_xor(c1, 32);
        c2 += __shfl_xor(c2, 16); c2 += __shfl_xor(c2, 32);
        if (q == 0) {
            c12p[idx * 32 + p]      = c1;
            c12p[idx * 32 + 16 + p] = c2;
        }
    }
}

// ---------------- reduce c12 partials: c12[0..31]=c1, c12[32..63]=c2 ----------------
__global__ __launch_bounds__(64)
void k_c12(const float* __restrict__ c12p, float* __restrict__ c12)
{
    const int i = threadIdx.x;
    const int half = i >> 5, r = i & 31;
    const int n = r >> 4, rr = r & 15;
    float s = 0.f;
    for (int kk = 0; kk < 64; ++kk)
        s += c12p[(kk * 2 + n) * 32 + half * 16 + rr];
    c12[i] = s;
}

// ---------------- fused: LN-folded down-proj + GELU + up-proj + residual (MFMA) ----------------
// 16 rows/block, 512 threads, full-M 16x16 tiles, all lanes active in epilogue.
__global__ __launch_bounds__(512, 4)
void k_fused(const float* __restrict__ x, const float* __restrict__ bd,
             const float* __restrict__ bu, const unsigned int* __restrict__ wuf,
             const unsigned int* __restrict__ wdpf, const float* __restrict__ c12,
             float* __restrict__ out)
{
    __shared__ unsigned int xs[ROWS * 1024];      // 64 KB bf16 x, XOR-swizzled rows
    __shared__ float Sp[8][16][16];               // 8 KB down-proj partials [wave][col r][row m]
    __shared__ unsigned short a_sh[ROWS][NR];     // 1 KB activations bf16
    __shared__ float mu_s[ROWS], rs_s[ROWS];

    const int tid = threadIdx.x;
    const int w = tid >> 6, l = tid & 63;
    const int p = l & 15, q = l >> 4;
    const long row0 = (long)blockIdx.x * ROWS;

    // ---- Phase A: stream x once, fp32 stats, bf16 pack -> LDS (swizzled) ----
    #pragma unroll
    for (int rp = 0; rp < 2; ++rp) {
        const int row = w * 2 + rp;
        const float* xr = x + (row0 + row) * D;
        float s = 0.f, s2 = 0.f;
        #pragma unroll
        for (int it = 0; it < 8; ++it) {
            const int j = it * 256 + l * 4;
            float4 v = *(const float4*)(xr + j);
            uint2 pkk;
            pkk.x = pk2(v.x, v.y);
            pkk.y = pk2(v.z, v.w);
            const int byte = (row * 4096 + j * 2) ^ (row << 4);
            *(uint2*)((char*)xs + byte) = pkk;
            s  += v.x + v.y + v.z + v.w;
            s2 += v.x * v.x + v.y * v.y + v.z * v.z + v.w * v.w;
        }
        #pragma unroll
        for (int off = 32; off >= 1; off >>= 1) {
            s  += __shfl_xor(s, off);
            s2 += __shfl_xor(s2, off);
        }
        if (l == 0) {
            const float mu  = s * (1.0f / D);
            const float var = s2 * (1.0f / D) - mu * mu;
            mu_s[row] = mu;
            rs_s[row] = rsqrtf(var + 1e-5f);
        }
    }
    __syncthreads();

    // ---- Phase B: S = x @ wdp via MFMA. wave w: K-split (w&3) x n-half (w>>2) ----
    {
        const int ks = w & 3, n = w >> 2;
        f32x4 acc = {0.f, 0.f, 0.f, 0.f};
        #pragma unroll 4
        for (int t = 0; t < 16; ++t) {
            const int byte = (p * 4096 + (ks * 512 + t * 32) * 2 + q * 16) ^ (p << 4);
            const bf16x8 af = *(const bf16x8*)((const char*)xs + byte);
            const int kk = ks * 16 + t;
            const bf16x8 bf = *(const bf16x8*)&wdpf[(kk * 2 + n) * 256 + l * 4];
            acc = __builtin_amdgcn_mfma_f32_16x16x32_bf16(af, bf, acc, 0, 0, 0);
        }
        *(f32x4*)&Sp[w][p][q * 4] = acc;   // D: col r = p, rows m = q*4+reg
    }
    __syncthreads();

    // ---- GELU: y = rstd*(S - mu*c1) + c2 + bd ; a = gelu(y) -> bf16 ----
    {
        const int m = tid >> 5, r = tid & 31;      // 512 threads = 16 rows x 32 r
        const int n = r >> 4, rr = r & 15;
        const float S = Sp[4 * n + 0][rr][m] + Sp[4 * n + 1][rr][m]
                      + Sp[4 * n + 2][rr][m] + Sp[4 * n + 3][rr][m];
        const float y = rs_s[m] * (S - mu_s[m] * c12[r]) + c12[32 + r] + bd[r];
        const float a = 0.5f * y * (1.0f + erff(y * 0.70710678118654752f));
        a_sh[m][r] = (unsigned short)f2bf(a);
    }
    __syncthreads();

    // ---- Phase C: out = x + bu + (a @ wu), transposed so each lane owns 4
    // consecutive j of one out row (float4 residual read + float4 NT store) ----
    {
        const bf16x8 afc = *(const bf16x8*)((const char*)a_sh + p * 64 + q * 16);
        const long xbase = (row0 + p) * D;
        const f32x4 z = {0.f, 0.f, 0.f, 0.f};
        #pragma unroll 4
        for (int t = 0; t < 16; ++t) {
            const int j0 = w * 256 + t * 16;
            const bf16x8 bw = *(const bf16x8*)&wuf[(w * 16 + t) * 256 + l * 4];
            f32x4 dd = __builtin_amdgcn_mfma_f32_16x16x32_bf16(bw, afc, z, 0, 0, 0);
            const int jj = j0 + q * 4;
            const float4 xv = *(const float4*)(x + xbase + jj);   // L2/L3-hot re-read
            const float4 bv = *(const float4*)(bu + jj);
            f32x4 o;
            o[0] = xv.x + bv.x + dd[0];
            o[1] = xv.y + bv.y + dd[1];
            o[2] = xv.z + bv.z + dd[2];
            o[3] = xv.w + bv.w + dd[3];
            __builtin_nontemporal_store(o, (f32x4*)(out + xbase + jj));
        }
    }
}

extern "C" void kernel_launch(void* const* d_in, const int* in_sizes, int n_in,
                              void* d_out, int out_size, void* d_ws, size_t ws_size,
                              hipStream_t stream) {
    (void)n_in; (void)ws_size; (void)out_size;
    const float* x     = (const float*)d_in[0];
    const float* gamma = (const float*)d_in[1];
    const float* beta  = (const float*)d_in[2];
    const float* wd    = (const float*)d_in[3];
    const float* bd    = (const float*)d_in[4];
    const float* wu    = (const float*)d_in[5];
    const float* bu    = (const float*)d_in[6];
    float* out = (float*)d_out;

    unsigned int* wuf  = (unsigned int*)d_ws;      // 128 KB
    unsigned int* wdpf = wuf + 32768;              // 128 KB
    float* c12p = (float*)(wdpf + 32768);          // 16 KB
    float* c12  = c12p + 4096;                     // 256 B

    const int nrows  = in_sizes[0] / D;            // 16384
    const int blocks = nrows / ROWS;               // 1024

    hipLaunchKernelGGL(k_prep,  dim3(256),    dim3(64),  0, stream,
                       wd, gamma, beta, wu, wuf, wdpf, c12p);
    hipLaunchKernelGGL(k_c12,   dim3(1),      dim3(64),  0, stream, c12p, c12);
    hipLaunchKernelGGL(k_fused, dim3(blocks), dim3(512), 0, stream,
                       x, bd, bu, wuf, wdpf, c12, out);
}

// Round 6
// 273.113 us; speedup vs baseline: 1.1185x; 1.0044x over previous
//
#include <hip/hip_runtime.h>
#include <math.h>

#define D     2048
#define NR    32

typedef short bf16x8 __attribute__((ext_vector_type(8)));
typedef float f32x4  __attribute__((ext_vector_type(4)));

__device__ __forceinline__ unsigned int f2bf(float f) {
    unsigned int u = __float_as_uint(f);
    return (u + 0x7FFFu + ((u >> 16) & 1u)) >> 16;   // RNE bf16, low 16
}
__device__ __forceinline__ unsigned int pk2(float a, float b) {
    return f2bf(a) | (f2bf(b) << 16);
}

// ---------------- prep: build fragment-layout bf16 weights + LN-fold vectors ----------------
// blocks 0..127: wuf[tile t][lane l][e] = bf16(wu[(l>>4)*8+e][t*16 + (l&15)])
// blocks 128..255: wdpf[(kk,n)][lane l][e] = bf16(gamma[k]*wd[k][n*16+(l&15)]), k=kk*32+(l>>4)*8+e
//                  + partial c1 (colsum gamma.wd) / c2 (colsum beta.wd) per (kk,n)
__global__ __launch_bounds__(64)
void k_prep(const float* __restrict__ wd, const float* __restrict__ gamma,
            const float* __restrict__ beta, const float* __restrict__ wu,
            unsigned int* __restrict__ wuf, unsigned int* __restrict__ wdpf,
            float* __restrict__ c12p)
{
    const int l = threadIdx.x;
    const int q = l >> 4, p = l & 15;
    const int b = blockIdx.x;
    if (b < 128) {
        const int t = b;
        float v[8];
        #pragma unroll
        for (int e = 0; e < 8; ++e)
            v[e] = wu[(q * 8 + e) * D + t * 16 + p];
        uint4 pk;
        pk.x = pk2(v[0], v[1]); pk.y = pk2(v[2], v[3]);
        pk.z = pk2(v[4], v[5]); pk.w = pk2(v[6], v[7]);
        *(uint4*)&wuf[(t * 64 + l) * 4] = pk;
    } else {
        const int idx = b - 128;           // 0..127 -> (kk, n)
        const int kk = idx >> 1, n = idx & 1;
        const int r = n * 16 + p;
        float wv[8];
        float c1 = 0.f, c2 = 0.f;
        #pragma unroll
        for (int e = 0; e < 8; ++e) {
            const int k = kk * 32 + q * 8 + e;
            const float wdv = wd[k * NR + r];
            wv[e] = gamma[k] * wdv;
            c1 += wv[e];
            c2 += beta[k] * wdv;
        }
        uint4 pk;
        pk.x = pk2(wv[0], wv[1]); pk.y = pk2(wv[2], wv[3]);
        pk.z = pk2(wv[4], wv[5]); pk.w = pk2(wv[6], wv[7]);
        *(uint4*)&wdpf[(idx * 64 + l) * 4] = pk;
        c1 += __shfl_xor(c1, 16); c1 += __shfl_xor(c1, 32);
        c2 += __shfl_xor(c2, 16); c2 += __shfl_xor(c2, 32);
        if (q == 0) {
            c12p[idx * 32 + p]      = c1;
            c12p[idx * 32 + 16 + p] = c2;
        }
    }
}

// ---------------- reduce c12 partials: c12[0..31]=c1, c12[32..63]=c2 ----------------
__global__ __launch_bounds__(64)
void k_c12(const float* __restrict__ c12p, float* __restrict__ c12)
{
    const int i = threadIdx.x;
    const int half = i >> 5, r = i & 31;
    const int n = r >> 4, rr = r & 15;
    float s = 0.f;
    for (int kk = 0; kk < 64; ++kk)
        s += c12p[(kk * 2 + n) * 32 + half * 16 + rr];
    c12[i] = s;
}

// ---------------- k1: LN-folded down-proj + GELU -> a (bf16 pairs) ----------------
// Block = 16 rows, 4 waves = 4 K-slices. No LDS staging of x: fragments loaded
// straight from global into registers; stats from the same registers; ONE barrier.
__global__ __launch_bounds__(256, 4)
void k1_down(const float* __restrict__ x, const float* __restrict__ bd,
             const unsigned int* __restrict__ wdpf, const float* __restrict__ c12,
             unsigned int* __restrict__ a_pk)
{
    __shared__ float Sp[4][2][16][16];    // 8 KB  [wave][n][r-col][row]
    __shared__ float sred[4][16][2];      // 512 B [wave][row][s,s2]

    const int tid = threadIdx.x;
    const int w = tid >> 6, l = tid & 63;
    const int p = l & 15, q = l >> 4;
    const long row0 = (long)blockIdx.x * 16;

    const float* xr = x + (row0 + p) * D + w * 512 + q * 8;
    f32x4 acc0 = {0.f, 0.f, 0.f, 0.f}, acc1 = {0.f, 0.f, 0.f, 0.f};
    float s = 0.f, s2 = 0.f;

    #pragma unroll 4
    for (int t = 0; t < 16; ++t) {
        const float4 v0 = *(const float4*)(xr + t * 32);
        const float4 v1 = *(const float4*)(xr + t * 32 + 4);
        s  += v0.x + v0.y + v0.z + v0.w + v1.x + v1.y + v1.z + v1.w;
        s2 += v0.x * v0.x + v0.y * v0.y + v0.z * v0.z + v0.w * v0.w
            + v1.x * v1.x + v1.y * v1.y + v1.z * v1.z + v1.w * v1.w;
        union { uint4 u; bf16x8 h; } cvt;
        cvt.u.x = pk2(v0.x, v0.y); cvt.u.y = pk2(v0.z, v0.w);
        cvt.u.z = pk2(v1.x, v1.y); cvt.u.w = pk2(v1.z, v1.w);
        const int kk = w * 16 + t;
        const bf16x8 b0 = *(const bf16x8*)&wdpf[(kk * 2 + 0) * 256 + l * 4];
        const bf16x8 b1 = *(const bf16x8*)&wdpf[(kk * 2 + 1) * 256 + l * 4];
        acc0 = __builtin_amdgcn_mfma_f32_16x16x32_bf16(cvt.h, b0, acc0, 0, 0, 0);
        acc1 = __builtin_amdgcn_mfma_f32_16x16x32_bf16(cvt.h, b1, acc1, 0, 0, 0);
    }

    // stats: reduce over q (lane bits 4,5) -> per-row partial for this K-slice
    s  += __shfl_xor(s, 16);  s  += __shfl_xor(s, 32);
    s2 += __shfl_xor(s2, 16); s2 += __shfl_xor(s2, 32);
    if (q == 0) { sred[w][p][0] = s; sred[w][p][1] = s2; }
    *(f32x4*)&Sp[w][0][p][q * 4] = acc0;   // D: col r = p(+16n), rows m = q*4+reg
    *(f32x4*)&Sp[w][1][p][q * 4] = acc1;
    __syncthreads();

    // GELU: thread -> (row m, r-pair rp). y = rstd*(S - mu*c1) + c2 + bd; a bf16-packed.
    {
        const int m = tid >> 4, rp = tid & 15;
        float ssum = 0.f, s2sum = 0.f;
        #pragma unroll
        for (int ww = 0; ww < 4; ++ww) {
            ssum  += sred[ww][m][0];
            s2sum += sred[ww][m][1];
        }
        const float mu   = ssum * (1.0f / D);
        const float var  = s2sum * (1.0f / D) - mu * mu;
        const float rstd = rsqrtf(var + 1e-5f);
        float av[2];
        #pragma unroll
        for (int i = 0; i < 2; ++i) {
            const int r = rp * 2 + i;
            const int n = r >> 4, rr = r & 15;
            const float S = Sp[0][n][rr][m] + Sp[1][n][rr][m]
                          + Sp[2][n][rr][m] + Sp[3][n][rr][m];
            const float y = rstd * (S - mu * c12[r]) + c12[32 + r] + bd[r];
            av[i] = 0.5f * y * (1.0f + erff(y * 0.70710678118654752f));
        }
        a_pk[(row0 + m) * 16 + rp] = pk2(av[0], av[1]);   // normal store: keep L2-hot
    }
}

// ---------------- k2: up-proj + residual. Zero LDS, zero barriers, pure stream. ----------------
// Block = one 16-row tile, 4 waves = 4 column-quarters (512 cols each).
__global__ __launch_bounds__(256, 4)
void k2_up(const float* __restrict__ x, const unsigned int* __restrict__ a_pk,
           const unsigned int* __restrict__ wuf, const float* __restrict__ bu,
           float* __restrict__ out)
{
    const int tid = threadIdx.x;
    const int w = tid >> 6, l = tid & 63;
    const int p = l & 15, q = l >> 4;
    const long row0 = (long)blockIdx.x * 16;

    // B-operand: a[row p][r = q*8 .. q*8+7] bf16 (1 KB contiguous per wave)
    const bf16x8 afc = *(const bf16x8*)&a_pk[(row0 + p) * 16 + q * 4];
    const long xbase = (row0 + p) * D;
    const f32x4 z = {0.f, 0.f, 0.f, 0.f};

    #pragma unroll 4
    for (int t = 0; t < 32; ++t) {
        const int jt = w * 32 + t;             // global 16-col tile index
        const int jj = jt * 16 + q * 4;
        const bf16x8 bw = *(const bf16x8*)&wuf[jt * 256 + l * 4];   // L2-hot
        f32x4 dd = __builtin_amdgcn_mfma_f32_16x16x32_bf16(bw, afc, z, 0, 0, 0);
        const float4 xv = *(const float4*)(x + xbase + jj);         // HBM stream
        const float4 bv = *(const float4*)(bu + jj);
        f32x4 o;
        o[0] = xv.x + bv.x + dd[0];
        o[1] = xv.y + bv.y + dd[1];
        o[2] = xv.z + bv.z + dd[2];
        o[3] = xv.w + bv.w + dd[3];
        __builtin_nontemporal_store(o, (f32x4*)(out + xbase + jj));
    }
}

extern "C" void kernel_launch(void* const* d_in, const int* in_sizes, int n_in,
                              void* d_out, int out_size, void* d_ws, size_t ws_size,
                              hipStream_t stream) {
    (void)n_in; (void)ws_size; (void)out_size;
    const float* x     = (const float*)d_in[0];
    const float* gamma = (const float*)d_in[1];
    const float* beta  = (const float*)d_in[2];
    const float* wd    = (const float*)d_in[3];
    const float* bd    = (const float*)d_in[4];
    const float* wu    = (const float*)d_in[5];
    const float* bu    = (const float*)d_in[6];
    float* out = (float*)d_out;

    unsigned int* wuf  = (unsigned int*)d_ws;      // 128 KB
    unsigned int* wdpf = wuf + 32768;              // 128 KB
    float* c12p = (float*)(wdpf + 32768);          // 16 KB
    float* c12  = c12p + 4096;                     // 256 B
    unsigned int* a_pk = (unsigned int*)(c12 + 64);// 1 MB (16384 rows x 16 uints)

    const int nrows  = in_sizes[0] / D;            // 16384
    const int tiles  = nrows / 16;                 // 1024

    hipLaunchKernelGGL(k_prep,  dim3(256),   dim3(64),  0, stream,
                       wd, gamma, beta, wu, wuf, wdpf, c12p);
    hipLaunchKernelGGL(k_c12,   dim3(1),     dim3(64),  0, stream, c12p, c12);
    hipLaunchKernelGGL(k1_down, dim3(tiles), dim3(256), 0, stream,
                       x, bd, wdpf, c12, a_pk);
    hipLaunchKernelGGL(k2_up,   dim3(tiles), dim3(256), 0, stream,
                       x, a_pk, wuf, bu, out);
}